// Round 10
// baseline (256.357 us; speedup 1.0000x reference)
//
#include <hip/hip_runtime.h>
#include <hip/hip_bf16.h>

#define NN 50000
#define NE 800000
#define DIN 128
#define DEIN 32
#define PD 192          // P row: [0:64) f_ni, [64:128) f_nj, [128:192) h_src(node proj)
#define NEG_SLOPE 0.2f

typedef __bf16 bf16x8 __attribute__((ext_vector_type(8)));
typedef __bf16 bf16x4 __attribute__((ext_vector_type(4)));
typedef float f32x4 __attribute__((ext_vector_type(4)));
using bf16 = __hip_bfloat16;

__device__ inline float b2f(__bf16 b) {
    unsigned short u = __builtin_bit_cast(unsigned short, b);
    return __uint_as_float((unsigned)u << 16);
}

__device__ inline bf16x8 load8_f32_to_bf16(const float* p) {
    f32x4 a = *reinterpret_cast<const f32x4*>(p);
    f32x4 b = *reinterpret_cast<const f32x4*>(p + 4);
    bf16x8 r;
#pragma unroll
    for (int j = 0; j < 4; j++) {
        r[j]     = (__bf16)a[j];
        r[j + 4] = (__bf16)b[j];
    }
    return r;
}

// ---------------- K1: P = nfeats @ [W_ni | W_nj | W_node] (+ zero counts) --------------
// 512 threads / 8 waves / 128 rows. Swapped-operand MFMA: D[wcol][node] ->
// lane holds node=lo, cols hi*4..+3 -> packed bf16x4 stores (12/thread).
__global__ __launch_bounds__(512) void k_node_gemm(
    const float* __restrict__ nfeats,
    const float* __restrict__ Wni, const float* __restrict__ Wnj,
    const float* __restrict__ Wnode,
    bf16* __restrict__ P, int* __restrict__ counts)
{
    __shared__ __align__(16) __bf16 sW[192][136];   // 52.2KB, [col][k]
    const int t = threadIdx.x;
    const int lane = t & 63;
    const int wid  = t >> 6;
    const int lo = lane & 15, hi = lane >> 4;

    {   // fused: zero the histogram buffer
        int z = blockIdx.x * 512 + t;
        if (z < NN) counts[z] = 0;
    }

    const float* tabs[3] = {Wni, Wnj, Wnode};
#pragma unroll
    for (int tb = 0; tb < 3; tb++) {
#pragma unroll
        for (int q = 0; q < 4; q++) {
            int flat = t + q * 512;             // 2048 f32x4 per table
            int k  = flat >> 4;
            int c4 = (flat & 15) * 4;
            f32x4 w4 = *reinterpret_cast<const f32x4*>(&tabs[tb][k * 64 + c4]);
#pragma unroll
            for (int i = 0; i < 4; i++)
                sW[tb * 64 + c4 + i][k] = (__bf16)w4[i];
        }
    }

    const int rbase = blockIdx.x * 128 + wid * 16;
    const int myrow = rbase + lo;
    bf16x8 afrag[4];
#pragma unroll
    for (int kk = 0; kk < 4; kk++) {
        int row = myrow >= NN ? NN - 1 : myrow;
        afrag[kk] = load8_f32_to_bf16(&nfeats[(size_t)row*DIN + kk*32 + hi*8]);
    }
    __syncthreads();

#pragma unroll
    for (int ct = 0; ct < 12; ct++) {
        f32x4 acc = {0.f, 0.f, 0.f, 0.f};
#pragma unroll
        for (int kk = 0; kk < 4; kk++) {
            bf16x8 bfrag = *reinterpret_cast<const bf16x8*>(&sW[ct*16 + lo][kk*32 + hi*8]);
            // swapped: D[wcol][node], node = lane&15, wcol = hi*4+r
            acc = __builtin_amdgcn_mfma_f32_16x16x32_bf16(bfrag, afrag[kk], acc, 0, 0, 0);
        }
        bf16x4 pk;
#pragma unroll
        for (int r = 0; r < 4; r++) pk[r] = (__bf16)acc[r];
        if (myrow < NN)
            *reinterpret_cast<bf16x4*>(&P[(size_t)myrow*PD + ct*16 + hi*4]) = pk;
    }
}

// ---------------- CSR build ----------------
__global__ void k_hist(const int* __restrict__ dst, int* __restrict__ counts, int e) {
    int i = blockIdx.x * blockDim.x + threadIdx.x;
    if (i < e) atomicAdd(&counts[dst[i]], 1);
}

__global__ __launch_bounds__(256) void k_bsum(const int* __restrict__ counts,
                                              int* __restrict__ bsum, int n) {
    __shared__ int ws[4];
    const int gid = blockIdx.x * 256 + threadIdx.x;
    const int lane = threadIdx.x & 63, wid = threadIdx.x >> 6;
    int v = (gid < n) ? counts[gid] : 0;
#pragma unroll
    for (int s = 1; s < 64; s <<= 1) v += __shfl_xor(v, s);
    if (lane == 0) ws[wid] = v;
    __syncthreads();
    if (threadIdx.x == 0) bsum[blockIdx.x] = ws[0] + ws[1] + ws[2] + ws[3];
}

__global__ __launch_bounds__(256) void k_bscan(const int* __restrict__ bsum,
                                               int* __restrict__ bpre,
                                               int* __restrict__ offsets, int nb) {
    __shared__ int ws[4];
    const int t = threadIdx.x, lane = t & 63, wid = t >> 6;
    int v = (t < nb) ? bsum[t] : 0;
    int sc = v;
#pragma unroll
    for (int s = 1; s < 64; s <<= 1) { int u = __shfl_up(sc, s); if (lane >= s) sc += u; }
    if (lane == 63) ws[wid] = sc;
    __syncthreads();
    int woff = 0;
    for (int k = 0; k < wid; k++) woff += ws[k];
    if (t < nb) bpre[t] = woff + sc - v;
    if (t == 0) offsets[NN] = NE;
}

__global__ __launch_bounds__(256) void k_apply(const int* __restrict__ counts,
                                               const int* __restrict__ bpre,
                                               int* __restrict__ offsets,
                                               int* __restrict__ cursor, int n) {
    __shared__ int ws[4];
    const int gid = blockIdx.x * 256 + threadIdx.x;
    const int t = threadIdx.x, lane = t & 63, wid = t >> 6;
    int v = (gid < n) ? counts[gid] : 0;
    int sc = v;
#pragma unroll
    for (int s = 1; s < 64; s <<= 1) { int u = __shfl_up(sc, s); if (lane >= s) sc += u; }
    if (lane == 63) ws[wid] = sc;
    __syncthreads();
    int woff = 0;
    for (int k = 0; k < wid; k++) woff += ws[k];
    const int ex = bpre[blockIdx.x] + woff + sc - v;
    if (gid < n) { offsets[gid] = ex; cursor[gid] = ex; }
}

// scatter: CSR slot p -> edge id and permuted src
__global__ void k_scatter(const int* __restrict__ dst, const int* __restrict__ src,
                          int* __restrict__ cursor, int* __restrict__ eidx,
                          int* __restrict__ srcp, int e) {
    int i = blockIdx.x * blockDim.x + threadIdx.x;
    if (i < e) {
        int p = atomicAdd(&cursor[dst[i]], 1);
        eidx[p] = i;
        srcp[p] = src[i];
    }
}

// ---------------- K2: fused edge stage (swapped-operand MFMA, no LDS staging) ---------
// 512 threads / 8 waves / 128 edges. D[wcol][edge]: lane = (edge lo, colgrp hi).
// P_i/P_j read direct to regs in matching layout; f_out = 4 x f32x4 from acc;
// logit = dot + 2 shfl; el = one f32x4 store per edge.
__global__ __launch_bounds__(512) void k_edge(
    const float* __restrict__ efeats,
    const float* __restrict__ Wf,     // [32][64] f32
    const float* __restrict__ attn,   // [64] f32
    const float* __restrict__ bias,   // [64] f32
    const bf16* __restrict__ P,       // [NN][192] bf16
    const int* __restrict__ src, const int* __restrict__ dst,
    float* __restrict__ f_out,        // [NE][64] f32
    float* __restrict__ el)           // [NE][4] = exp(logit)
{
    __shared__ __align__(16) __bf16 sWf[64][32];     // 4KB, [col][k]
    const int t = threadIdx.x;
    const int lane = t & 63, wid = t >> 6;
    const int lo = lane & 15, hi = lane >> 4;
    const int e0w = blockIdx.x * 128 + wid * 16;
    const int myedge = e0w + lo;

    // stage Wf transposed (all threads)
    {
        int k  = t >> 4;
        int cc = (t & 15) * 4;
        f32x4 w4 = *reinterpret_cast<const f32x4*>(&Wf[k * 64 + cc]);
#pragma unroll
        for (int i = 0; i < 4; i++) sWf[cc + i][k] = (__bf16)w4[i];
    }

    // B-operand: edge features (edge = col = lo)
    bf16x8 afrag = load8_f32_to_bf16(&efeats[(size_t)myedge*DEIN + hi*8]);

    // indices + P rows direct to registers (layout matches D)
    const int si = src[myedge];
    const int di = dst[myedge];
    bf16x4 pi[4], pj[4];
#pragma unroll
    for (int ct = 0; ct < 4; ct++) {
        pi[ct] = *reinterpret_cast<const bf16x4*>(&P[(size_t)si*PD + ct*16 + hi*4]);
        pj[ct] = *reinterpret_cast<const bf16x4*>(&P[(size_t)di*PD + 64 + ct*16 + hi*4]);
    }

    f32x4 att4[4], bias4[4];
#pragma unroll
    for (int ct = 0; ct < 4; ct++) {
        att4[ct]  = *reinterpret_cast<const f32x4*>(&attn[ct*16 + hi*4]);
        bias4[ct] = *reinterpret_cast<const f32x4*>(&bias[ct*16 + hi*4]);
    }

    __syncthreads();   // sWf ready

    // A-operand: W^T fragments
    bf16x8 bfr[4];
#pragma unroll
    for (int ct = 0; ct < 4; ct++)
        bfr[ct] = *reinterpret_cast<const bf16x8*>(&sWf[ct*16 + lo][hi*8]);

    float ve0, ve1, ve2, ve3;
#pragma unroll
    for (int ct = 0; ct < 4; ct++) {
        f32x4 z = {0.f, 0.f, 0.f, 0.f};
        f32x4 d = __builtin_amdgcn_mfma_f32_16x16x32_bf16(bfr[ct], afrag, z, 0, 0, 0);
        f32x4 x;
#pragma unroll
        for (int i = 0; i < 4; i++) {
            float xv = d[i] + b2f(pi[ct][i]) + b2f(pj[ct][i]) + bias4[ct][i];
            x[i] = xv > 0.f ? xv : NEG_SLOPE * xv;
        }
        *reinterpret_cast<f32x4*>(&f_out[(size_t)myedge*64 + ct*16 + hi*4]) = x;
        float partial = x[0]*att4[ct][0] + x[1]*att4[ct][1]
                      + x[2]*att4[ct][2] + x[3]*att4[ct][3];
        partial += __shfl_xor(partial, 16);
        partial += __shfl_xor(partial, 32);
        if (ct == 0) ve0 = partial;
        else if (ct == 1) ve1 = partial;
        else if (ct == 2) ve2 = partial;
        else ve3 = partial;
    }
    if (hi == 0) {
        f32x4 ev = { __expf(ve0), __expf(ve1), __expf(ve2), __expf(ve3) };
        *reinterpret_cast<f32x4*>(&el[(size_t)myedge*4]) = ev;
    }
}

// ---------------- K4: single-pass aggregation (a=exp stored; no max needed) ----------
__global__ __launch_bounds__(256) void k_aggregate(
    const int* __restrict__ offsets, const int* __restrict__ eidx,
    const int* __restrict__ srcp, const float* __restrict__ el,
    const bf16* __restrict__ P, float* __restrict__ h_out)
{
    const int lane = threadIdx.x & 63;
    const int wid  = threadIdx.x >> 6;
    const int n = blockIdx.x * 4 + wid;
    if (n >= NN) return;
    const int off0 = offsets[n], off1 = offsets[n + 1];
    const int h4 = lane & 3;        // head for load phase
    const int slot4 = lane >> 2;    // 16 slots

    float denp = 0.f, acc = 0.f;
    for (int c0 = off0; c0 < off1; c0 += 16) {
        const int cnt = off1 - c0;
        float a_ld = 0.f;
        int s_ld = 0;
        if (slot4 < cnt) {
            const int e = eidx[c0 + slot4];
            a_ld = el[(size_t)e*4 + h4];
            s_ld = srcp[c0 + slot4];
        }
        denp += a_ld;
#pragma unroll
        for (int q = 0; q < 16; q++) {
            const float wq = __shfl(a_ld, (q << 2) | (lane >> 4));
            const int   sq = __shfl(s_ld, q << 2);
            acc += wq * __bfloat162float(P[(size_t)sq*PD + 128 + lane]);
        }
    }
    denp += __shfl_xor(denp, 4);
    denp += __shfl_xor(denp, 8);
    denp += __shfl_xor(denp, 16);
    denp += __shfl_xor(denp, 32);
    const float den = __shfl(denp, lane >> 4);
    h_out[(size_t)n*64 + lane] = (off1 > off0) ? acc / den : 0.f;
}

extern "C" void kernel_launch(void* const* d_in, const int* in_sizes, int n_in,
                              void* d_out, int out_size, void* d_ws, size_t ws_size,
                              hipStream_t stream) {
    const float* nfeats = (const float*)d_in[0];
    const float* efeats = (const float*)d_in[1];
    const float* Wni    = (const float*)d_in[2];
    const float* Wnj    = (const float*)d_in[3];
    const float* Wfij   = (const float*)d_in[4];
    const float* Wnode  = (const float*)d_in[5];
    const float* attn   = (const float*)d_in[6];
    const float* bias   = (const float*)d_in[7];
    const int*   src    = (const int*)d_in[8];
    const int*   dst    = (const int*)d_in[9];

    float* h_out = (float*)d_out;                           // [NN*64]
    float* f_out = (float*)d_out + (size_t)NN * 64;         // [NE*64]

    char* ws = (char*)d_ws;
    size_t off = 0;
    auto carve = [&](size_t bytes) -> void* {
        void* p = ws + off;
        off = (off + bytes + 255) & ~(size_t)255;
        return p;
    };
    const int NB = (NN + 255) / 256;    // 196 scan blocks
    bf16*  P       = (bf16*) carve((size_t)NN * PD * sizeof(bf16));
    float* el      = (float*)carve((size_t)NE * 4 * sizeof(float));
    int*   counts  = (int*)  carve((size_t)NN * sizeof(int));
    int*   cursor  = (int*)  carve((size_t)NN * sizeof(int));
    int*   offsets = (int*)  carve((size_t)(NN + 1) * sizeof(int));
    int*   eidx    = (int*)  carve((size_t)NE * sizeof(int));
    int*   srcp    = (int*)  carve((size_t)NE * sizeof(int));
    int*   bsum    = (int*)  carve((size_t)NB * sizeof(int));
    int*   bpre    = (int*)  carve((size_t)NB * sizeof(int));
    (void)ws_size; (void)in_sizes; (void)n_in; (void)out_size;

    hipLaunchKernelGGL(k_node_gemm, dim3((NN + 127) / 128), dim3(512), 0, stream,
                       nfeats, Wni, Wnj, Wnode, P, counts);
    hipLaunchKernelGGL(k_hist, dim3((NE + 255) / 256), dim3(256), 0, stream,
                       dst, counts, NE);
    hipLaunchKernelGGL(k_bsum, dim3(NB), dim3(256), 0, stream, counts, bsum, NN);
    hipLaunchKernelGGL(k_bscan, dim3(1), dim3(256), 0, stream, bsum, bpre, offsets, NB);
    hipLaunchKernelGGL(k_apply, dim3(NB), dim3(256), 0, stream,
                       counts, bpre, offsets, cursor, NN);
    hipLaunchKernelGGL(k_scatter, dim3((NE + 255) / 256), dim3(256), 0, stream,
                       dst, src, cursor, eidx, srcp, NE);
    hipLaunchKernelGGL(k_edge, dim3(NE / 128), dim3(512), 0, stream,
                       efeats, Wfij, attn, bias, P, src, dst, f_out, el);
    hipLaunchKernelGGL(k_aggregate, dim3((NN + 3) / 4), dim3(256), 0, stream,
                       offsets, eidx, srcp, el, P, h_out);
}